// Round 1
// baseline (1351.822 us; speedup 1.0000x reference)
//
#include <hip/hip_runtime.h>

#define BB 8
#define NN 200000
#define HH 480
#define WW 640
#define HWSZ (HH * WW)

// ---------------------------------------------------------------------------
// Stage 1: per-event bilinear scatter of {w, w*tw} into acc[(b*2+pol)][pix][2]
// ---------------------------------------------------------------------------
__global__ void ev_scatter(const float4* __restrict__ ev,   // [B*N] (ts,y,x,p)
                           const float2* __restrict__ pm,   // [B*N] (p, 1-p)
                           const float*  __restrict__ flow, // [B,2,H,W]
                           float* __restrict__ acc,         // [B*2][HW][2]
                           float tref) {
    int gid = blockIdx.x * blockDim.x + threadIdx.x;
    if (gid >= BB * NN) return;
    int b = gid / NN;

    float4 e = ev[gid];          // ts, y, x, pol(+/-1)
    float2 m = pm[gid];
    int pol = (m.x > 0.5f) ? 0 : 1;

    int gidx = (int)(e.y * (float)WW + e.z);
    const float* fb = flow + (size_t)b * 2 * HWSZ;
    float fx = fb[gidx];          // channel 0 = x-flow
    float fy = fb[HWSZ + gidx];   // channel 1 = y-flow

    float dt = tref - e.x;
    float wy = e.y + dt * fy * 640.0f;   // flow_scaling = max(H,W) = 640
    float wx = e.z + dt * fx * 640.0f;
    float tw = (tref == 1.0f) ? e.x : (1.0f - e.x);

    float ty = floorf(wy), lx = floorf(wx);
    float ry = wy - ty,    rx = wx - lx;   // fractional parts in [0,1)

    float* a = acc + (size_t)(b * 2 + pol) * HWSZ * 2;

    #pragma unroll
    for (int cy = 0; cy < 2; ++cy) {
        float iy = ty + (float)cy;
        if (iy < 0.0f || iy >= (float)HH) continue;
        float wyw = cy ? ry : (1.0f - ry);
        #pragma unroll
        for (int cx = 0; cx < 2; ++cx) {
            float ix = lx + (float)cx;
            if (ix < 0.0f || ix >= (float)WW) continue;
            float wxw = cx ? rx : (1.0f - rx);
            float wgt = wyw * wxw;
            int lin = ((int)iy) * WW + (int)ix;
            atomicAdd(&a[lin * 2 + 0], wgt);
            atomicAdd(&a[lin * 2 + 1], wgt * tw);
        }
    }
}

// ---------------------------------------------------------------------------
// Block-reduce helper: wave shuffle + LDS, one atomicAdd per block
// ---------------------------------------------------------------------------
__device__ __forceinline__ void block_reduce_add(float v, float* out) {
    #pragma unroll
    for (int off = 32; off > 0; off >>= 1)
        v += __shfl_down(v, off, 64);
    __shared__ float ls[4];            // 256 threads = 4 waves
    int lane = threadIdx.x & 63;
    int wid  = threadIdx.x >> 6;
    if (lane == 0) ls[wid] = v;
    __syncthreads();
    if (threadIdx.x == 0) {
        float s = ls[0] + ls[1] + ls[2] + ls[3];
        atomicAdd(out, s);
    }
}

// ---------------------------------------------------------------------------
// Stage 2: sum over pixels of (wt / (w + 1e-9))^2
// ---------------------------------------------------------------------------
__global__ void ratio_reduce(const float* __restrict__ acc, float* __restrict__ out) {
    const size_t total = (size_t)BB * 2 * HWSZ;
    float s = 0.0f;
    for (size_t i = (size_t)blockIdx.x * blockDim.x + threadIdx.x; i < total;
         i += (size_t)gridDim.x * blockDim.x) {
        float w  = acc[i * 2 + 0];
        float wt = acc[i * 2 + 1];
        float r = wt / (w + 1e-9f);
        s += r * r;
    }
    block_reduce_add(s, out);
}

// ---------------------------------------------------------------------------
// Stage 3: Charbonnier smoothness over flow: diffs along H and along W
// ---------------------------------------------------------------------------
__global__ void smooth_reduce(const float* __restrict__ flow, float* __restrict__ out) {
    const size_t total = (size_t)BB * 2 * HWSZ;
    float s = 0.0f;
    for (size_t i = (size_t)blockIdx.x * blockDim.x + threadIdx.x; i < total;
         i += (size_t)gridDim.x * blockDim.x) {
        int w = (int)(i % WW);
        int h = (int)((i / WW) % HH);
        float v = flow[i];
        if (h < HH - 1) {
            float d = v - flow[i + WW];
            s += sqrtf(d * d + 1e-6f);
        }
        if (w < WW - 1) {
            float d = v - flow[i + 1];
            s += sqrtf(d * d + 1e-6f);
        }
    }
    block_reduce_add(s, out);
}

extern "C" void kernel_launch(void* const* d_in, const int* in_sizes, int n_in,
                              void* d_out, int out_size, void* d_ws, size_t ws_size,
                              hipStream_t stream) {
    const float*  flow = (const float*)d_in[0];   // [B,2,H,W]
    const float4* ev   = (const float4*)d_in[1];  // [B,N,4]
    const float2* pm   = (const float2*)d_in[2];  // [B,N,2]
    float* out = (float*)d_out;
    float* acc = (float*)d_ws;                    // per-pass: B*2*HW*2 floats

    const size_t acc_bytes = (size_t)BB * 2 * HWSZ * 2 * sizeof(float);

    hipMemsetAsync(out, 0, sizeof(float), stream);

    const int evThreads = 256;
    const int evBlocks  = (BB * NN + evThreads - 1) / evThreads;
    const int rBlocks   = 1024;

    // tref = 1 pass, then tref = 0 pass (buffer reused)
    for (int t = 0; t < 2; ++t) {
        float tref = (t == 0) ? 1.0f : 0.0f;
        hipMemsetAsync(acc, 0, acc_bytes, stream);
        ev_scatter<<<evBlocks, evThreads, 0, stream>>>(ev, pm, flow, acc, tref);
        ratio_reduce<<<rBlocks, 256, 0, stream>>>(acc, out);
    }
    smooth_reduce<<<rBlocks, 256, 0, stream>>>(flow, out);
}

// Round 2
// 721.104 us; speedup vs baseline: 1.8747x; 1.8747x over previous
//
#include <hip/hip_runtime.h>
#include <hip/hip_fp16.h>

#define BB 8
#define NN 200000
#define HH 480
#define WW 640
#define HWSZ (HH * WW)

// blocks per batch for the scatter (ceil(NN/256))
#define EV_CHUNKS ((NN + 255) / 256)

// ---------------------------------------------------------------------------
// Stage 0: interleave flow [B,2,H,W] -> fxy [B,H,W] float2 (fx, fy)
// ---------------------------------------------------------------------------
__global__ void flow_interleave(const float* __restrict__ flow,
                                float2* __restrict__ fxy) {
    const size_t total = (size_t)BB * HWSZ;
    for (size_t i = (size_t)blockIdx.x * blockDim.x + threadIdx.x; i < total;
         i += (size_t)gridDim.x * blockDim.x) {
        size_t b = i / HWSZ, pix = i % HWSZ;
        const float* fb = flow + b * 2 * HWSZ;
        fxy[i] = make_float2(fb[pix], fb[HWSZ + pix]);
    }
}

// ---------------------------------------------------------------------------
// Stage 1: per-event bilinear scatter of packed {w, w*tw} (half2) into
// acc[b][pol][pix]. Batch affinity: b = blockIdx.x % 8 -> XCD b.
// ---------------------------------------------------------------------------
__global__ void ev_scatter(const float4* __restrict__ ev,   // [B*N] (ts,y,x,p)
                           const float2* __restrict__ pm,   // [B*N] (p, 1-p)
                           const float2* __restrict__ fxy,  // [B*HW] (fx,fy)
                           __half2* __restrict__ acc,       // [B*2][HW] packed
                           float tref) {
    int b     = blockIdx.x & 7;          // XCD-affinity: batch b on XCD b
    int chunk = blockIdx.x >> 3;
    int e = chunk * blockDim.x + threadIdx.x;
    if (e >= NN) return;
    int gid = b * NN + e;

    float4 ev4 = ev[gid];                // ts, y, x, pol(+/-1)
    float2 m   = pm[gid];
    int pol = (m.x > 0.5f) ? 0 : 1;

    int gidx = (int)(ev4.y * (float)WW + ev4.z);
    float2 f = fxy[(size_t)b * HWSZ + gidx];

    float dt = tref - ev4.x;
    float wy = ev4.y + dt * f.y * 640.0f;   // flow_scaling = max(H,W) = 640
    float wx = ev4.z + dt * f.x * 640.0f;
    float tw = (tref == 1.0f) ? ev4.x : (1.0f - ev4.x);

    float ty = floorf(wy), lx = floorf(wx);
    float ry = wy - ty,    rx = wx - lx;

    __half2* a = acc + (size_t)(b * 2 + pol) * HWSZ;

    #pragma unroll
    for (int cy = 0; cy < 2; ++cy) {
        float iy = ty + (float)cy;
        if (iy < 0.0f || iy >= (float)HH) continue;
        float wyw = cy ? ry : (1.0f - ry);
        #pragma unroll
        for (int cx = 0; cx < 2; ++cx) {
            float ix = lx + (float)cx;
            if (ix < 0.0f || ix >= (float)WW) continue;
            float wgt = wyw * (cx ? rx : (1.0f - rx));
            int lin = ((int)iy) * WW + (int)ix;
            unsafeAtomicAdd(&a[lin], __floats2half2_rn(wgt, wgt * tw));
        }
    }
}

// ---------------------------------------------------------------------------
// Block-reduce helper: wave shuffle + LDS, one atomicAdd per block
// ---------------------------------------------------------------------------
__device__ __forceinline__ void block_reduce_add(float v, float* out) {
    #pragma unroll
    for (int off = 32; off > 0; off >>= 1)
        v += __shfl_down(v, off, 64);
    __shared__ float ls[4];            // 256 threads = 4 waves
    int lane = threadIdx.x & 63;
    int wid  = threadIdx.x >> 6;
    if (lane == 0) ls[wid] = v;
    __syncthreads();
    if (threadIdx.x == 0) {
        float s = ls[0] + ls[1] + ls[2] + ls[3];
        atomicAdd(out, s);
    }
}

// ---------------------------------------------------------------------------
// Stage 2: sum over pixels of (wt / (w + 1e-9))^2, batch-affinity mapping
// so reads hit the XCD-local dirty L2 lines.
// ---------------------------------------------------------------------------
#define RB_PER_BATCH 96
__global__ void ratio_reduce(const __half2* __restrict__ acc,
                             float* __restrict__ out) {
    int b = blockIdx.x & 7;
    int k = blockIdx.x >> 3;
    const size_t per_batch = (size_t)2 * HWSZ;     // 2 pol planes
    const __half2* ab = acc + (size_t)b * per_batch;
    float s = 0.0f;
    for (size_t i = (size_t)k * blockDim.x + threadIdx.x; i < per_batch;
         i += (size_t)RB_PER_BATCH * blockDim.x) {
        float2 v = __half22float2(ab[i]);
        float r = v.y / (v.x + 1e-9f);
        s += r * r;
    }
    block_reduce_add(s, out);
}

// ---------------------------------------------------------------------------
// Stage 3: Charbonnier smoothness over flow
// ---------------------------------------------------------------------------
__global__ void smooth_reduce(const float* __restrict__ flow,
                              float* __restrict__ out) {
    const size_t total = (size_t)BB * 2 * HWSZ;
    float s = 0.0f;
    for (size_t i = (size_t)blockIdx.x * blockDim.x + threadIdx.x; i < total;
         i += (size_t)gridDim.x * blockDim.x) {
        int w = (int)(i % WW);
        int h = (int)((i / WW) % HH);
        float v = flow[i];
        if (h < HH - 1) {
            float d = v - flow[i + WW];
            s += sqrtf(d * d + 1e-6f);
        }
        if (w < WW - 1) {
            float d = v - flow[i + 1];
            s += sqrtf(d * d + 1e-6f);
        }
    }
    block_reduce_add(s, out);
}

extern "C" void kernel_launch(void* const* d_in, const int* in_sizes, int n_in,
                              void* d_out, int out_size, void* d_ws, size_t ws_size,
                              hipStream_t stream) {
    const float*  flow = (const float*)d_in[0];   // [B,2,H,W]
    const float4* ev   = (const float4*)d_in[1];  // [B,N,4]
    const float2* pm   = (const float2*)d_in[2];  // [B,N,2]
    float* out = (float*)d_out;

    // workspace layout: acc (half2, 19.66 MB) | fxy (float2, 19.66 MB)
    __half2* acc = (__half2*)d_ws;
    const size_t acc_bytes = (size_t)BB * 2 * HWSZ * sizeof(__half2);
    float2* fxy = (float2*)((char*)d_ws + acc_bytes);

    hipMemsetAsync(out, 0, sizeof(float), stream);

    flow_interleave<<<2048, 256, 0, stream>>>(flow, fxy);

    const int evBlocks = 8 * EV_CHUNKS;
    const int rBlocks  = 8 * RB_PER_BATCH;

    for (int t = 0; t < 2; ++t) {
        float tref = (t == 0) ? 1.0f : 0.0f;
        hipMemsetAsync(acc, 0, acc_bytes, stream);
        ev_scatter<<<evBlocks, 256, 0, stream>>>(ev, pm, fxy, acc, tref);
        ratio_reduce<<<rBlocks, 256, 0, stream>>>(acc, out);
    }
    smooth_reduce<<<1024, 256, 0, stream>>>(flow, out);
}